// Round 2
// baseline (476.432 us; speedup 1.0000x reference)
//
#include <hip/hip_runtime.h>
#include <hip/hip_bf16.h>

#define TT 2048
#define HD 1024
#define NE 8
#define ID 2048

typedef short bf16x8 __attribute__((ext_vector_type(8)));
typedef float f32x4 __attribute__((ext_vector_type(4)));

__device__ __forceinline__ float bflo(unsigned v){ return __uint_as_float(v << 16); }
__device__ __forceinline__ float bfhi(unsigned v){ return __uint_as_float(v & 0xFFFF0000u); }
__device__ __forceinline__ unsigned f2bf(float f){
  unsigned u = __float_as_uint(f);
  return (u + 0x7FFFu + ((u >> 16) & 1u)) >> 16;  // RNE, low 16 bits valid
}
__device__ __forceinline__ float gelu_t(float x){
  float x3 = x * x * x;
  return 0.5f * x * (1.f + tanhf(0.7978845608028654f * (x + 0.044715f * x3)));
}

// ---------------- Router: logits -> softcap -> top2 -> softmax -> gather lists
__global__ __launch_bounds__(64) void router_kernel(
    const float* __restrict__ x,    // [T,H] fp32
    const float* __restrict__ gw,   // [H,E] fp32
    int* __restrict__ counts,       // [E]
    int* __restrict__ list_ak,      // [E,T]  (t*2+slot)
    float* __restrict__ wlist)      // [E,T]
{
  int t = blockIdx.x;
  int lane = threadIdx.x;
  float acc[NE];
  #pragma unroll
  for (int e = 0; e < NE; ++e) acc[e] = 0.f;
  const float* xr = x + (size_t)t * HD;
  #pragma unroll
  for (int j = 0; j < HD / 64; ++j) {
    int h = j * 64 + lane;
    float xv = xr[h];
    float4 g0 = *(const float4*)(gw + (size_t)h * NE);
    float4 g1 = *(const float4*)(gw + (size_t)h * NE + 4);
    acc[0] += xv * g0.x; acc[1] += xv * g0.y;
    acc[2] += xv * g0.z; acc[3] += xv * g0.w;
    acc[4] += xv * g1.x; acc[5] += xv * g1.y;
    acc[6] += xv * g1.z; acc[7] += xv * g1.w;
  }
  #pragma unroll
  for (int e = 0; e < NE; ++e) {
    float v = acc[e];
    #pragma unroll
    for (int off = 32; off > 0; off >>= 1) v += __shfl_xor(v, off, 64);
    acc[e] = v;
  }
  if (lane == 0) {
    float lg[NE];
    #pragma unroll
    for (int e = 0; e < NE; ++e) lg[e] = tanhf(acc[e] * (1.0f / 30.0f));
    int i0 = 0;
    #pragma unroll
    for (int e = 1; e < NE; ++e) if (lg[e] > lg[i0]) i0 = e;
    int i1 = (i0 == 0) ? 1 : 0;
    #pragma unroll
    for (int e = 0; e < NE; ++e) if (e != i0 && lg[e] > lg[i1]) i1 = e;
    float e1 = __expf(lg[i1] - lg[i0]);   // <= 1
    float w0 = 1.f / (1.f + e1);
    float w1 = 1.f - w0;
    int p0 = atomicAdd(counts + i0, 1);
    list_ak[i0 * TT + p0] = t * 2;
    wlist[i0 * TT + p0] = w0;
    int p1 = atomicAdd(counts + i1, 1);
    list_ak[i1 * TT + p1] = t * 2 + 1;
    wlist[i1 * TT + p1] = w1;
  }
}

// ---------------- Gathered expert GEMM: dst[ak, n] = (w?) * sum_k src[row(ak), k] * W_e[k, n]
// 128x128 tile, 4 waves each 64x64 via 4x4 mfma_f32_16x16x32_bf16, BK=32.
// SrcT: float (x) or unsigned short (bf16 act). W fp32. Dst bf16 or fp32.
template <typename SrcT, int OUT_BF16>
__global__ __launch_bounds__(256) void moe_gemm(
    const SrcT* __restrict__ src,
    const float* __restrict__ W,             // [E][K][N] fp32
    void* __restrict__ dstv,
    const int* __restrict__ counts,
    const int* __restrict__ list_ak,
    const float* __restrict__ wlist,
    int K, int N, int srcShift, int srcStride, int ldo, int applyW)
{
  int e = blockIdx.z;
  int nCnt = counts[e];
  int m0 = blockIdx.y * 128;
  if (m0 >= nCnt) return;
  int c0 = blockIdx.x * 128;
  const float* We = W + (size_t)e * K * N;

  __shared__ unsigned short As[128 * 32];  // bf16 [row][k], row = 64B
  __shared__ unsigned int Bt[128 * 20];    // bf16 B^T: [n][k-pairs], 20-dword padded rows

  int tid = threadIdx.x;
  int wave = tid >> 6, lane = tid & 63;
  int wy = wave >> 1, wx = wave & 1;

  // A staging: 2 threads per row, 16 elements each
  int arow = tid >> 1, ahalf = tid & 1;
  int apos = m0 + arow;
  long abase = -1;
  if (apos < nCnt) {
    int ak = list_ak[e * TT + apos];
    abase = (long)(ak >> srcShift) * srcStride;
  }
  int kc = wave, nd = lane;  // B staging: 8k x 2n per thread

  f32x4 acc[4][4];
  f32x4 zed = {0.f, 0.f, 0.f, 0.f};
  #pragma unroll
  for (int i = 0; i < 4; ++i)
    #pragma unroll
    for (int j = 0; j < 4; ++j) acc[i][j] = zed;

  for (int k0 = 0; k0 < K; k0 += 32) {
    // ---- stage A (gathered rows; zero out-of-range rows), convert to bf16
    #pragma unroll
    for (int s = 0; s < 2; ++s) {
      uint4 ov = make_uint4(0u, 0u, 0u, 0u);
      if (abase >= 0) {
        if constexpr (sizeof(SrcT) == 4) {
          const float* p = (const float*)src + abase + k0 + ahalf * 16 + s * 8;
          float4 v0 = *(const float4*)p;
          float4 v1 = *(const float4*)(p + 4);
          ov.x = f2bf(v0.x) | (f2bf(v0.y) << 16);
          ov.y = f2bf(v0.z) | (f2bf(v0.w) << 16);
          ov.z = f2bf(v1.x) | (f2bf(v1.y) << 16);
          ov.w = f2bf(v1.z) | (f2bf(v1.w) << 16);
        } else {
          ov = *(const uint4*)((const unsigned short*)src + abase + k0 + ahalf * 16 + s * 8);
        }
      }
      *(uint4*)(&As[arow * 32 + ahalf * 16 + s * 8]) = ov;
    }
    // ---- stage B with transpose-on-write (pack two k-rows per dword)
    {
      const float* Wk = We + (size_t)(k0 + kc * 8) * N + c0 + nd * 2;
      float2 wv[8];
      #pragma unroll
      for (int j = 0; j < 8; ++j) wv[j] = *(const float2*)(Wk + (size_t)j * N);
      unsigned lo[4], hi[4];
      #pragma unroll
      for (int jj = 0; jj < 4; ++jj) {
        float2 a = wv[2 * jj], b = wv[2 * jj + 1];
        lo[jj] = f2bf(a.x) | (f2bf(b.x) << 16);   // col n=2nd   : (k even, k odd)
        hi[jj] = f2bf(a.y) | (f2bf(b.y) << 16);   // col n=2nd+1 : (k even, k odd)
      }
      *(uint4*)(&Bt[(nd * 2 + 0) * 20 + kc * 4]) = make_uint4(lo[0], lo[1], lo[2], lo[3]);
      *(uint4*)(&Bt[(nd * 2 + 1) * 20 + kc * 4]) = make_uint4(hi[0], hi[1], hi[2], hi[3]);
    }
    __syncthreads();

    // ---- fragments + MFMA
    int q = lane >> 4, l15 = lane & 15;
    bf16x8 af[4], bfr[4];
    #pragma unroll
    for (int mt = 0; mt < 4; ++mt) {
      int row = wy * 64 + mt * 16 + l15;
      af[mt] = *(const bf16x8*)(&As[row * 32 + q * 8]);
    }
    #pragma unroll
    for (int nt = 0; nt < 4; ++nt) {
      int row = wx * 64 + nt * 16 + l15;
      bfr[nt] = *(const bf16x8*)(&Bt[row * 20 + q * 4]);
    }
    #pragma unroll
    for (int mt = 0; mt < 4; ++mt)
      #pragma unroll
      for (int nt = 0; nt < 4; ++nt)
        acc[mt][nt] = __builtin_amdgcn_mfma_f32_16x16x32_bf16(af[mt], bfr[nt], acc[mt][nt], 0, 0, 0);
    __syncthreads();
  }

  // ---- epilogue: C/D layout col=lane&15, row=quad*4+reg
  int col = lane & 15, rgrp = lane >> 4;
  #pragma unroll
  for (int mt = 0; mt < 4; ++mt) {
    #pragma unroll
    for (int r = 0; r < 4; ++r) {
      int mloc = wy * 64 + mt * 16 + rgrp * 4 + r;
      int pos = m0 + mloc;
      if (pos >= nCnt) continue;
      int ak = list_ak[e * TT + pos];
      float ws = applyW ? wlist[e * TT + pos] : 1.f;
      #pragma unroll
      for (int nt = 0; nt < 4; ++nt) {
        int ncol = c0 + wx * 64 + nt * 16 + col;
        float val = acc[mt][nt][r] * ws;
        if (OUT_BF16)
          ((unsigned short*)dstv)[(size_t)ak * ldo + ncol] = (unsigned short)f2bf(val);
        else
          ((float*)dstv)[(size_t)ak * ldo + ncol] = val;
      }
    }
  }
}

// ---------------- act = gelu(g) * u, in place into g (bf16)
__global__ void act_kernel(unsigned short* __restrict__ g,
                           const unsigned short* __restrict__ u)
{
  const int total = TT * 2 * ID / 8;  // uint4 chunks
  for (int i = blockIdx.x * blockDim.x + threadIdx.x; i < total;
       i += gridDim.x * blockDim.x) {
    uint4 gv = *(const uint4*)(g + (size_t)i * 8);
    uint4 uv = *(const uint4*)(u + (size_t)i * 8);
    unsigned gs[4] = {gv.x, gv.y, gv.z, gv.w};
    unsigned us[4] = {uv.x, uv.y, uv.z, uv.w};
    unsigned os[4];
    #pragma unroll
    for (int p = 0; p < 4; ++p) {
      float a0 = gelu_t(bflo(gs[p])) * bflo(us[p]);
      float a1 = gelu_t(bfhi(gs[p])) * bfhi(us[p]);
      os[p] = f2bf(a0) | (f2bf(a1) << 16);
    }
    *(uint4*)(g + (size_t)i * 8) = make_uint4(os[0], os[1], os[2], os[3]);
  }
}

// ---------------- out[t,h] = yw[2t,h] + yw[2t+1,h]  (fp32)
__global__ void combine_kernel(const float* __restrict__ yw,
                               float* __restrict__ out)
{
  const int total = TT * HD / 4;
  for (int i = blockIdx.x * blockDim.x + threadIdx.x; i < total;
       i += gridDim.x * blockDim.x) {
    int i4 = i * 4;
    int t = i4 >> 10;         // / HD
    int h = i4 & (HD - 1);
    float4 a = *(const float4*)(yw + ((size_t)(2 * t)) * HD + h);
    float4 b = *(const float4*)(yw + ((size_t)(2 * t + 1)) * HD + h);
    float4 o;
    o.x = a.x + b.x; o.y = a.y + b.y; o.z = a.z + b.z; o.w = a.w + b.w;
    *(float4*)(out + (size_t)i4) = o;
  }
}

extern "C" void kernel_launch(void* const* d_in, const int* in_sizes, int n_in,
                              void* d_out, int out_size, void* d_ws, size_t ws_size,
                              hipStream_t stream) {
  const float* x  = (const float*)d_in[0];  // [T,H]
  const float* gw = (const float*)d_in[1];  // [H,E]
  const float* wg = (const float*)d_in[2];  // [E,H,I]
  const float* wu = (const float*)d_in[3];  // [E,H,I]
  const float* wd = (const float*)d_in[4];  // [E,I,H]
  float* out = (float*)d_out;

  char* ws = (char*)d_ws;
  int* counts   = (int*)ws;                       // 32 B (zeroed below)
  int* list_ak  = (int*)(ws + 256);               // 64 KB
  float* wlist  = (float*)(ws + 256 + 65536);     // 64 KB
  size_t off = 256 + 2 * 65536;                   // 131328, 16B-aligned
  unsigned short* g_buf = (unsigned short*)(ws + off);          // 16 MB bf16 [T*2, I]
  char* region2 = ws + off + (size_t)TT * 2 * ID * 2;           // 16 MB
  unsigned short* u_buf = (unsigned short*)region2;             // bf16 [T*2, I]
  float* yw = (float*)region2;  // fp32 [T*2, H]; aliases u (dead after act)

  hipMemsetAsync(counts, 0, 256, stream);
  router_kernel<<<TT, 64, 0, stream>>>(x, gw, counts, list_ak, wlist);

  dim3 blk(256);
  dim3 gA(ID / 128, TT / 128, NE);  // (16,16,8)
  // g = X @ Wg_e   (gather token rows: row = ak>>1, stride H) -> bf16
  moe_gemm<float, 1><<<gA, blk, 0, stream>>>(x, wg, g_buf, counts, list_ak, wlist,
                                             HD, ID, 1, HD, ID, 0);
  // u = X @ Wu_e -> bf16
  moe_gemm<float, 1><<<gA, blk, 0, stream>>>(x, wu, u_buf, counts, list_ak, wlist,
                                             HD, ID, 1, HD, ID, 0);
  act_kernel<<<2048, 256, 0, stream>>>(g_buf, u_buf);
  dim3 gD(HD / 128, TT / 128, NE);  // (8,16,8)
  // yw = w * (act @ Wd_e)  (gather act rows: row = ak, stride I) -> fp32
  moe_gemm<unsigned short, 0><<<gD, blk, 0, stream>>>(g_buf, wd, yw, counts, list_ak, wlist,
                                                      ID, HD, 0, ID, HD, 1);
  combine_kernel<<<1024, 256, 0, stream>>>(yw, out);
}